// Round 3
// baseline (395.143 us; speedup 1.0000x reference)
//
#include <hip/hip_runtime.h>
#include <math.h>

// DiceLoss fused kernel for MI355X — round 5: kill the collective barrier
// drains (R2 geometry + double-buffered LDS + raw s_barrier + full prefetch).
// B=32, C=1, H=W=1024 fp32. loss = mean_b(1 - (2*I_b + 1e-3)/(M_b + 1e-3))
//   I_b = sum sigmoid(o)*t*w,  M_b = sum (t+sigmoid(o))*w,
//   w = 1 + 5*|boxavg31(t) - t|, zero-padded, always /961.
//
// R3/R4 post-mortem: occupancy hypothesis dead. R3 (8 blk/CU, spills) 207us;
// R4 (8 blk/CU, spill-free) 163us — BOTH worse than R2's 4 blk/CU 137us.
// More waves don't help because every wave in a block stalls together at the
// two __syncthreads per iteration, each compiling to s_waitcnt vmcnt(0)
// lgkmcnt(0) + s_barrier: a collective drain of all in-flight loads
// (~700-1400 exposed cycles/iter explains 20K cyc/iter wall with pipes <30%).
// R5 changes (vs R2):
//  1. vbuf double-buffered -> ONE barrier per iteration (buffer re-write two
//     iterations later is ordered by the intervening barrier).
//  2. Raw s_barrier + explicit "s_waitcnt lgkmcnt(0)" fence: LDS visibility
//     needs lgkm only. Global prefetches now wait per-wave at their USE
//     (compiler-counted vmcnt), one full phase after issue - never a
//     collective vmcnt(0).
//  3. Sub-rows prefetched too (sA/qS): phase A is load-free register math.

namespace {
constexpr int Bn = 32;
constexpr int Hn = 1024;
constexpr int Wn = 1024;
constexpr int Rn = 15;           // kernel radius (K=31)
constexpr int TX = 256;          // tile width in outputs
constexpr int YS = 128;          // tile height in outputs (back to R2)
constexpr int NB = YS / 8;       // 8-row batches per tile
constexpr int NCOL = TX + 32;    // staged columns (30-halo rounded to 32)
constexpr int PHYSW = (NCOL / 8) * 12;   // 432 floats per padded LDS row
constexpr float INV_KK = 1.0f / 961.0f;
}

__device__ __forceinline__ int phys(int i) { return i + ((i >> 3) << 2); }

// x-guard precomputed per thread; y folded to one unsigned compare.
__device__ __forceinline__ float ldcol(const float* p, int y, int col, bool xok) {
    return (xok && (unsigned)y < (unsigned)Hn) ? p[(size_t)y * Wn + col] : 0.0f;
}

// Workgroup barrier that fences LDS only (no vmcnt(0) drain).
// "memory" clobbers stop the compiler moving LDS ops across; the explicit
// lgkmcnt(0) guarantees ds_writes are visible before any wave proceeds.
__device__ __forceinline__ void lds_barrier() {
    asm volatile("s_waitcnt lgkmcnt(0)" ::: "memory");
    __builtin_amdgcn_s_barrier();
    asm volatile("" ::: "memory");
}

__global__ __launch_bounds__(256, 4)
void dice_main(const float* __restrict__ logits, const float* __restrict__ tgt,
               float* __restrict__ acc)
{
    __shared__ __align__(16) float vbuf[2][8 * PHYSW];
    __shared__ float red[8];

    const int bid = blockIdx.x;
    const int b   = bid >> 5;          // 32 tiles per batch image
    const int rem = bid & 31;
    const int x0  = (rem >> 3) * TX;   // 4 x-tiles
    const int y0  = (rem & 7) * YS;    // 8 y-tiles
    const int t   = threadIdx.x;

    const float* tb = tgt    + (size_t)b * Hn * Wn;
    const float* ob = logits + (size_t)b * Hn * Wn;

    // Vertical-sum column ownership: thread t owns staged col t; t<32 also 256+t.
    const int  col0 = x0 - Rn + t;
    const bool has2 = (t < 32);
    const int  col1 = col0 + 256;
    const bool xok0 = (col0 >= 0) && (col0 < Wn);
    const bool xok1 = (col1 >= 0) && (col1 < Wn);
    const int  pt   = phys(t);
    const int  pt2  = phys(256 + t);

    // Phase-B strip identity (fixed per thread across all batches).
    const int rr = t >> 5;             // row within 8-row batch
    const int jj = t & 31;             // 8-wide x strip
    const int xb = x0 + (jj << 3);

    // ---- init: vertical box sum for output row y0 (rows y0-15..y0+15) ----
    float vs0 = 0.0f, vs1 = 0.0f;
    for (int yy = y0 - Rn; yy <= y0 + Rn; ++yy) {
        vs0 += ldcol(tb, yy, col0, xok0);
        if (has2) vs1 += ldcol(tb, yy, col1, xok1);
    }

    // ---- prologue prefetch for batch 0: add rows, sub rows, t/o strips ----
    float pA[8], qA[8], sA[8], qS[8];
    #pragma unroll
    for (int r = 0; r < 8; ++r) {
        pA[r] = ldcol(tb, y0 + r + Rn, col0, xok0);
        sA[r] = ldcol(tb, y0 + r - Rn - 1, col0, xok0);
        qA[r] = has2 ? ldcol(tb, y0 + r + Rn, col1, xok1) : 0.0f;
        qS[r] = has2 ? ldcol(tb, y0 + r - Rn - 1, col1, xok1) : 0.0f;
    }
    float4 ct0, ct1, co0, co1;
    {
        const float* tp = tb + (size_t)(y0 + rr) * Wn + xb;
        const float* op = ob + (size_t)(y0 + rr) * Wn + xb;
        ct0 = ((const float4*)tp)[0]; ct1 = ((const float4*)tp)[1];
        co0 = ((const float4*)op)[0]; co1 = ((const float4*)op)[1];
    }

    float acc_i = 0.0f, acc_m = 0.0f;

    for (int it = 0; it < NB; ++it) {
        const int ya = y0 + it * 8;
        float* vb = vbuf[it & 1];

        // ---- phase A: pure register math + LDS writes (no loads) ----
        #pragma unroll
        for (int r = 0; r < 8; ++r) {
            if (it > 0 || r > 0) {
                vs0 += pA[r] - sA[r];
                if (has2) vs1 += qA[r] - qS[r];
            }
            vb[r * PHYSW + pt] = vs0;
            if (has2) vb[r * PHYSW + pt2] = vs1;
        }

        lds_barrier();   // single barrier per iteration; LDS-only fence

        // ---- phase B ----
        // Issue next-batch prefetches FIRST; they are consumed one full
        // phase later (phase A / phase B of it+1) via per-wave counted
        // vmcnt waits — no collective drain anywhere.
        float4 nt0, nt1, no0, no1;
        if (it + 1 < NB) {
            #pragma unroll
            for (int r = 0; r < 8; ++r) {
                pA[r] = ldcol(tb, ya + 8 + r + Rn, col0, xok0);
                sA[r] = ldcol(tb, ya + 8 + r - Rn - 1, col0, xok0);
                if (has2) {
                    qA[r] = ldcol(tb, ya + 8 + r + Rn, col1, xok1);
                    qS[r] = ldcol(tb, ya + 8 + r - Rn - 1, col1, xok1);
                }
            }
            const float* tp = tb + (size_t)(ya + 8 + rr) * Wn + xb;
            const float* op = ob + (size_t)(ya + 8 + rr) * Wn + xb;
            nt0 = ((const float4*)tp)[0]; nt1 = ((const float4*)tp)[1];
            no0 = ((const float4*)op)[0]; no1 = ((const float4*)op)[1];
        }

        // Horizontal 31-tap: 10 aligned b128 LDS reads + register slide.
        {
            const float* vrow = &vb[rr * PHYSW];
            float w[40];
            #pragma unroll
            for (int k = 0; k < 10; ++k) {
                const float4 q = *(const float4*)&vrow[phys((jj << 3) + (k << 2))];
                w[4 * k + 0] = q.x; w[4 * k + 1] = q.y;
                w[4 * k + 2] = q.z; w[4 * k + 3] = q.w;
            }

            const float tc[8] = {ct0.x, ct0.y, ct0.z, ct0.w, ct1.x, ct1.y, ct1.z, ct1.w};
            const float oc[8] = {co0.x, co0.y, co0.z, co0.w, co1.x, co1.y, co1.z, co1.w};

            // balanced-ish initial 31-sum
            float s0 = 0.0f, s1 = 0.0f, s2 = 0.0f, s3 = 0.0f;
            #pragma unroll
            for (int c = 0; c < 28; c += 4) {
                s0 += w[c]; s1 += w[c + 1]; s2 += w[c + 2]; s3 += w[c + 3];
            }
            float s = (s0 + s1) + (s2 + s3) + w[28] + w[29] + w[30];
            #pragma unroll
            for (int m = 0; m < 8; ++m) {
                if (m > 0) s += w[30 + m] - w[m - 1];
                const float avg = s * INV_KK;
                const float wt  = 1.0f + 5.0f * fabsf(avg - tc[m]);
                const float sg  = 1.0f / (1.0f + __expf(-oc[m]));
                acc_i += sg * tc[m] * wt;
                acc_m += (tc[m] + sg) * wt;
            }
        }

        // rotate t/o double buffer (no trailing barrier: next phase A only
        // touches vbuf[(it+1)&1], and the next lds_barrier orders reuse).
        if (it + 1 < NB) { ct0 = nt0; ct1 = nt1; co0 = no0; co1 = no1; }
    }

    // ---- block reduction ----
    #pragma unroll
    for (int off = 32; off > 0; off >>= 1) {
        acc_i += __shfl_down(acc_i, off);
        acc_m += __shfl_down(acc_m, off);
    }
    const int lane = t & 63;
    const int wv   = t >> 6;
    if (lane == 0) { red[wv * 2] = acc_i; red[wv * 2 + 1] = acc_m; }
    __syncthreads();
    if (t == 0) {
        atomicAdd(&acc[2 * b],     red[0] + red[2] + red[4] + red[6]);
        atomicAdd(&acc[2 * b + 1], red[1] + red[3] + red[5] + red[7]);
    }
}

__global__ void dice_final(const float* __restrict__ acc, float* __restrict__ out)
{
    const int t = threadIdx.x;
    float l = 0.0f;
    if (t < Bn) {
        const float I = acc[2 * t];
        const float M = acc[2 * t + 1];
        l = 1.0f - (2.0f * I + 0.001f) / (M + 0.001f);
    }
    #pragma unroll
    for (int off = 32; off > 0; off >>= 1) l += __shfl_down(l, off);
    if (t == 0) out[0] = l * (1.0f / 32.0f);
}

extern "C" void kernel_launch(void* const* d_in, const int* in_sizes, int n_in,
                              void* d_out, int out_size, void* d_ws, size_t ws_size,
                              hipStream_t stream)
{
    const float* logits = (const float*)d_in[0];   // "output" in reference
    const float* target = (const float*)d_in[1];
    float* acc = (float*)d_ws;                     // 64 floats: (I_b, M_b) per batch

    hipMemsetAsync(d_ws, 0, 64 * sizeof(float), stream);
    dice_main<<<dim3(Bn * 32), dim3(256), 0, stream>>>(logits, target, acc);
    dice_final<<<dim3(1), dim3(64), 0, stream>>>(acc, (float*)d_out);
}

// Round 4
// 339.917 us; speedup vs baseline: 1.1625x; 1.1625x over previous
//
#include <hip/hip_runtime.h>
#include <math.h>

// DiceLoss fused kernel for MI355X — round 6: single lgkm-only barrier,
// register-neutral (R5's structure, R2's register footprint).
// B=32, C=1, H=W=1024 fp32. loss = mean_b(1 - (2*I_b + 1e-3)/(M_b + 1e-3))
//   I_b = sum sigmoid(o)*t*w,  M_b = sum (t+sigmoid(o))*w,
//   w = 1 + 5*|boxavg31(t) - t|, zero-padded, always /961.
//
// R5 post-mortem: sA/qS prefetch (16 extra live floats) pushed VGPR to the
// 64 cliff -> 49MB scratch spills (WRITE_SIZE), FETCH +139MB, dur 218us.
// The barrier restructure itself was never cleanly tested.
// R6 = R5 minus sA/qS: sub-rows are direct loads in phase A again (L2/L3
// warm: loaded as add-rows 4 iterations earlier; R2's FETCH=268MB proves
// no HBM re-fetch). Keeps: double-buffered vbuf + ONE raw s_barrier with
// lgkmcnt-only fence per iteration (vs R2's two full vmcnt(0) drains).
// Global prefetches issued top of phase B are consumed one full phase later
// via per-wave counted vmcnt - never a collective drain.
// Validity check for this round: WRITE_SIZE must be back to ~64B.

namespace {
constexpr int Bn = 32;
constexpr int Hn = 1024;
constexpr int Wn = 1024;
constexpr int Rn = 15;           // kernel radius (K=31)
constexpr int TX = 256;          // tile width in outputs
constexpr int YS = 128;          // tile height in outputs
constexpr int NB = YS / 8;       // 8-row batches per tile
constexpr int NCOL = TX + 32;    // staged columns (30-halo rounded to 32)
constexpr int PHYSW = (NCOL / 8) * 12;   // 432 floats per padded LDS row
constexpr float INV_KK = 1.0f / 961.0f;
}

__device__ __forceinline__ int phys(int i) { return i + ((i >> 3) << 2); }

// x-guard precomputed per thread; y folded to one unsigned compare.
__device__ __forceinline__ float ldcol(const float* p, int y, int col, bool xok) {
    return (xok && (unsigned)y < (unsigned)Hn) ? p[(size_t)y * Wn + col] : 0.0f;
}

// Workgroup barrier that fences LDS only (no vmcnt(0) drain).
// "memory" clobbers stop the compiler moving LDS ops across; the explicit
// lgkmcnt(0) guarantees ds_writes are visible before any wave proceeds.
__device__ __forceinline__ void lds_barrier() {
    asm volatile("s_waitcnt lgkmcnt(0)" ::: "memory");
    __builtin_amdgcn_s_barrier();
    asm volatile("" ::: "memory");
}

__global__ __launch_bounds__(256, 4)
void dice_main(const float* __restrict__ logits, const float* __restrict__ tgt,
               float* __restrict__ acc)
{
    __shared__ __align__(16) float vbuf[2][8 * PHYSW];
    __shared__ float red[8];

    const int bid = blockIdx.x;
    const int b   = bid >> 5;          // 32 tiles per batch image
    const int rem = bid & 31;
    const int x0  = (rem >> 3) * TX;   // 4 x-tiles
    const int y0  = (rem & 7) * YS;    // 8 y-tiles
    const int t   = threadIdx.x;

    const float* tb = tgt    + (size_t)b * Hn * Wn;
    const float* ob = logits + (size_t)b * Hn * Wn;

    // Vertical-sum column ownership: thread t owns staged col t; t<32 also 256+t.
    const int  col0 = x0 - Rn + t;
    const bool has2 = (t < 32);
    const int  col1 = col0 + 256;
    const bool xok0 = (col0 >= 0) && (col0 < Wn);
    const bool xok1 = (col1 >= 0) && (col1 < Wn);
    const int  pt   = phys(t);
    const int  pt2  = phys(256 + t);

    // Phase-B strip identity (fixed per thread across all batches).
    const int rr = t >> 5;             // row within 8-row batch
    const int jj = t & 31;             // 8-wide x strip
    const int xb = x0 + (jj << 3);

    // ---- init: vertical box sum for output row y0 (rows y0-15..y0+15) ----
    float vs0 = 0.0f, vs1 = 0.0f;
    for (int yy = y0 - Rn; yy <= y0 + Rn; ++yy) {
        vs0 += ldcol(tb, yy, col0, xok0);
        if (has2) vs1 += ldcol(tb, yy, col1, xok1);
    }

    // ---- prefetch batch 0: vertical add-rows + phase-B t/o strips ----
    float pA[8], qA[8];
    #pragma unroll
    for (int r = 0; r < 8; ++r) {
        pA[r] = ldcol(tb, y0 + r + Rn, col0, xok0);
        qA[r] = has2 ? ldcol(tb, y0 + r + Rn, col1, xok1) : 0.0f;
    }
    float4 ct0, ct1, co0, co1;
    {
        const float* tp = tb + (size_t)(y0 + rr) * Wn + xb;
        const float* op = ob + (size_t)(y0 + rr) * Wn + xb;
        ct0 = ((const float4*)tp)[0]; ct1 = ((const float4*)tp)[1];
        co0 = ((const float4*)op)[0]; co1 = ((const float4*)op)[1];
    }

    float acc_i = 0.0f, acc_m = 0.0f;

    for (int it = 0; it < NB; ++it) {
        const int ya = y0 + it * 8;
        float* vb = vbuf[it & 1];

        // ---- phase A: consume prefetched add rows, direct L2/L3 sub loads ----
        #pragma unroll
        for (int r = 0; r < 8; ++r) {
            const int yr = ya + r;
            if (it > 0 || r > 0) {
                vs0 += pA[r] - ldcol(tb, yr - Rn - 1, col0, xok0);
                if (has2) vs1 += qA[r] - ldcol(tb, yr - Rn - 1, col1, xok1);
            }
            vb[r * PHYSW + pt] = vs0;
            if (has2) vb[r * PHYSW + pt2] = vs1;
        }

        lds_barrier();   // single barrier per iteration; LDS-only fence

        // ---- phase B ----
        // Issue next-batch prefetches FIRST; they are consumed one full
        // phase later via per-wave counted vmcnt waits - no collective drain.
        float4 nt0, nt1, no0, no1;
        if (it + 1 < NB) {
            #pragma unroll
            for (int r = 0; r < 8; ++r) {
                pA[r] = ldcol(tb, ya + 8 + r + Rn, col0, xok0);
                if (has2) qA[r] = ldcol(tb, ya + 8 + r + Rn, col1, xok1);
            }
            const float* tp = tb + (size_t)(ya + 8 + rr) * Wn + xb;
            const float* op = ob + (size_t)(ya + 8 + rr) * Wn + xb;
            nt0 = ((const float4*)tp)[0]; nt1 = ((const float4*)tp)[1];
            no0 = ((const float4*)op)[0]; no1 = ((const float4*)op)[1];
        }

        // Horizontal 31-tap: 10 aligned b128 LDS reads + register slide.
        {
            const float* vrow = &vb[rr * PHYSW];
            float w[40];
            #pragma unroll
            for (int k = 0; k < 10; ++k) {
                const float4 q = *(const float4*)&vrow[phys((jj << 3) + (k << 2))];
                w[4 * k + 0] = q.x; w[4 * k + 1] = q.y;
                w[4 * k + 2] = q.z; w[4 * k + 3] = q.w;
            }

            const float tc[8] = {ct0.x, ct0.y, ct0.z, ct0.w, ct1.x, ct1.y, ct1.z, ct1.w};
            const float oc[8] = {co0.x, co0.y, co0.z, co0.w, co1.x, co1.y, co1.z, co1.w};

            // balanced-ish initial 31-sum
            float s0 = 0.0f, s1 = 0.0f, s2 = 0.0f, s3 = 0.0f;
            #pragma unroll
            for (int c = 0; c < 28; c += 4) {
                s0 += w[c]; s1 += w[c + 1]; s2 += w[c + 2]; s3 += w[c + 3];
            }
            float s = (s0 + s1) + (s2 + s3) + w[28] + w[29] + w[30];
            #pragma unroll
            for (int m = 0; m < 8; ++m) {
                if (m > 0) s += w[30 + m] - w[m - 1];
                const float avg = s * INV_KK;
                const float wt  = 1.0f + 5.0f * fabsf(avg - tc[m]);
                const float sg  = 1.0f / (1.0f + __expf(-oc[m]));
                acc_i += sg * tc[m] * wt;
                acc_m += (tc[m] + sg) * wt;
            }
        }

        // rotate t/o double buffer (no trailing barrier: next phase A only
        // touches vbuf[(it+1)&1]; buffer reuse two iterations out is ordered
        // by the intervening collective barrier).
        if (it + 1 < NB) { ct0 = nt0; ct1 = nt1; co0 = no0; co1 = no1; }
    }

    // ---- block reduction ----
    #pragma unroll
    for (int off = 32; off > 0; off >>= 1) {
        acc_i += __shfl_down(acc_i, off);
        acc_m += __shfl_down(acc_m, off);
    }
    const int lane = t & 63;
    const int wv   = t >> 6;
    if (lane == 0) { red[wv * 2] = acc_i; red[wv * 2 + 1] = acc_m; }
    __syncthreads();
    if (t == 0) {
        atomicAdd(&acc[2 * b],     red[0] + red[2] + red[4] + red[6]);
        atomicAdd(&acc[2 * b + 1], red[1] + red[3] + red[5] + red[7]);
    }
}

__global__ void dice_final(const float* __restrict__ acc, float* __restrict__ out)
{
    const int t = threadIdx.x;
    float l = 0.0f;
    if (t < Bn) {
        const float I = acc[2 * t];
        const float M = acc[2 * t + 1];
        l = 1.0f - (2.0f * I + 0.001f) / (M + 0.001f);
    }
    #pragma unroll
    for (int off = 32; off > 0; off >>= 1) l += __shfl_down(l, off);
    if (t == 0) out[0] = l * (1.0f / 32.0f);
}

extern "C" void kernel_launch(void* const* d_in, const int* in_sizes, int n_in,
                              void* d_out, int out_size, void* d_ws, size_t ws_size,
                              hipStream_t stream)
{
    const float* logits = (const float*)d_in[0];   // "output" in reference
    const float* target = (const float*)d_in[1];
    float* acc = (float*)d_ws;                     // 64 floats: (I_b, M_b) per batch

    hipMemsetAsync(d_ws, 0, 64 * sizeof(float), stream);
    dice_main<<<dim3(Bn * 32), dim3(256), 0, stream>>>(logits, target, acc);
    dice_final<<<dim3(1), dim3(64), 0, stream>>>(acc, (float*)d_out);
}

// Round 5
// 311.394 us; speedup vs baseline: 1.2689x; 1.0916x over previous
//
#include <hip/hip_runtime.h>
#include <math.h>

// DiceLoss fused kernel for MI355X — round 7: LDS ring for t (load-once),
// phase A with ZERO global loads, register pressure structurally defused.
// B=32, C=1, H=W=1024 fp32. loss = mean_b(1 - (2*I_b + 1e-3)/(M_b + 1e-3))
//   I_b = sum sigmoid(o)*t*w,  M_b = sum (t+sigmoid(o))*w,
//   w = 1 + 5*|boxavg31(t) - t|, zero-padded box 31x31, always /961.
//
// R3-R6 post-mortem: occupancy (R4), barrier drains (R6) both disproven;
// every reg-prefetch attempt spilled at the 64-VGPR cliff imposed by
// __launch_bounds__(256,4). R7 restructures around LDS instead:
//  - 6-slot ring of raw t rows (8-row groups, 320 staged cols). Each t
//    element is read from global ONCE per block, staged one iteration
//    ahead (loads at top of phase B, ds_write after compute = T14 split),
//    and consumed from LDS as add-row, sub-row AND tc-strip.
//  - Phase A: pure LDS + VALU (no global loads on the critical path).
//  - OOB handled by clamped addresses + 0/1 mask multiplies (bitwise-
//    identical contributions to the old zero-select).
//  - LDS 75 KB -> 2 blocks/CU (LDS-capped), so launch_bounds(256,2) lifts
//    the VGPR cap to ~256: NO spill risk (validity gate: WRITE_SIZE ~64B).
//  - YS=256, grid=512: all blocks resident, prologue paid once.

namespace {
constexpr int Bn = 32;
constexpr int Hn = 1024;
constexpr int Wn = 1024;
constexpr int Rn = 15;            // kernel radius (K=31)
constexpr int TX = 256;           // tile width in outputs
constexpr int YS = 256;           // tile height in outputs
constexpr int NB = YS / 8;        // 8-row batches per tile (32)
constexpr int SC = 320;           // staged ring cols: image cols [x0-16, x0+303]
constexpr int PHYSW = 432;        // padded vbuf row (288 sums, phys layout)
constexpr float INV_KK = 1.0f / 961.0f;
}

__device__ __forceinline__ int phys(int i) { return i + ((i >> 3) << 2); }
// ring slot for an (possibly negative, possibly >=Hn virtual) row; groups of 8.
__device__ __forceinline__ int rslot(int row) { return ((row + 48) >> 3) % 6; }

__global__ __launch_bounds__(256, 2)
void dice_main(const float* __restrict__ logits, const float* __restrict__ tgt,
               float* __restrict__ acc)
{
    __shared__ __align__(16) float ring[6][8][SC];   // 61440 B raw t rows
    __shared__ __align__(16) float vbuf[8 * PHYSW];  // 13824 B vertical sums
    __shared__ float red[8];

    const int bid = blockIdx.x;
    const int b   = bid >> 4;          // 16 tiles per image
    const int rem = bid & 15;
    const int x0  = (rem >> 2) * TX;   // 4 x-tiles
    const int y0  = (rem & 3) * YS;    // 4 y-tiles
    const int t   = threadIdx.x;

    const float* tb = tgt    + (size_t)b * Hn * Wn;
    const float* ob = logits + (size_t)b * Hn * Wn;

    // Staging identity: thread t stages ring col j=t (image col x0-16+t);
    // t<64 also j=t+256 (image col x0+240+t). Addresses clamped; OOB data
    // is zeroed at consumption via masks.
    const bool st2 = (t < 64);
    const int  cs0 = min(max(x0 - 16 + t, 0), Wn - 1);
    const int  cs1 = min(max(x0 + 240 + t, 0), Wn - 1);

    // Sum-col identity: thread t owns sum col s=t (image col x0-15+t, ring
    // col j=t+1); t<32 also s=t+256 (ring col j=t+257).
    const bool  has2 = (t < 32);
    const float xm0  = (x0 - 15 + t >= 0 && x0 - 15 + t < Wn) ? 1.0f : 0.0f;
    const float xm1  = (x0 + 241 + t < Wn) ? 1.0f : 0.0f;
    const int   pt   = phys(t);
    const int   pt2  = phys(t + 256);

    // Phase-B strip identity.
    const int rr = t >> 5;             // row within 8-row batch
    const int jj = t & 31;             // 8-wide x strip
    const int xb = x0 + (jj << 3);

    // ---- prologue: stage groups covering rows y0-16 .. y0+23 (5 groups) ----
    #pragma unroll
    for (int gi = 0; gi < 5; ++gi) {
        const int row0 = y0 - 16 + gi * 8;
        const int sl   = rslot(row0);
        #pragma unroll
        for (int r = 0; r < 8; ++r) {
            const int row = min(max(row0 + r, 0), Hn - 1);
            const size_t off = (size_t)row * Wn;
            ring[sl][r][t] = tb[off + cs0];
            if (st2) ring[sl][r][t + 256] = tb[off + cs1];
        }
    }

    // o-strip prefetch for iter 0 (rows y0+rr, always in-bounds).
    float4 co0, co1;
    {
        const float* op = ob + (size_t)(y0 + rr) * Wn + xb;
        co0 = ((const float4*)op)[0]; co1 = ((const float4*)op)[1];
    }
    __syncthreads();

    // ---- init: vertical 31-sum for output row y0, read from ring ----
    float vs0 = 0.0f, vs1 = 0.0f;
    #pragma unroll
    for (int yy = -Rn; yy <= Rn; ++yy) {
        const int row = y0 + yy;                    // row < Hn always (y0<=768)
        const float m = (row >= 0) ? 1.0f : 0.0f;
        const int sl = rslot(row);
        const int ri = row & 7;
        vs0 += m * ring[sl][ri][t + 1];
        if (has2) vs1 += m * ring[sl][ri][t + 257];
    }

    float acc_i = 0.0f, acc_m = 0.0f;

    for (int it = 0; it < NB; ++it) {
        const int ya = y0 + it * 8;

        // ---- phase A: vs updates purely from LDS ring ----
        #pragma unroll
        for (int r = 0; r < 8; ++r) {
            if (it > 0 || r > 0) {
                const int rowa = ya + r + Rn;        // add row
                const int rows = ya + r - Rn - 1;    // sub row
                const float ma = (rowa < Hn) ? 1.0f : 0.0f;
                const float ms = (rows >= 0) ? 1.0f : 0.0f;
                const int sa = rslot(rowa), ia  = rowa & 7;
                const int ss = rslot(rows), is_ = rows & 7;
                vs0 += ma * ring[sa][ia][t + 1] - ms * ring[ss][is_][t + 1];
                if (has2)
                    vs1 += ma * ring[sa][ia][t + 257] - ms * ring[ss][is_][t + 257];
            }
            vbuf[r * PHYSW + pt] = vs0 * xm0;
            if (has2) vbuf[r * PHYSW + pt2] = vs1 * xm1;
        }
        __syncthreads();

        // ---- phase B ----
        // (1) Issue next-group staging loads + next o-strip FIRST (consumed
        //     ~a full phase later; per-wave counted vmcnt, no collective wait
        //     younger than ~1.5K cycles at the barrier).
        float stA[8], stB[8];
        float4 no0, no1;
        const bool more = (it + 1 < NB);
        if (more) {
            #pragma unroll
            for (int r = 0; r < 8; ++r) {
                const int row = min(ya + 24 + r, Hn - 1);   // group g+3
                const size_t off = (size_t)row * Wn;
                stA[r] = tb[off + cs0];
                if (st2) stB[r] = tb[off + cs1];
            }
            const float* op = ob + (size_t)(ya + 8 + rr) * Wn + xb;
            no0 = ((const float4*)op)[0]; no1 = ((const float4*)op)[1];
        }

        // (2) tc strip straight from the ring (rows ya..ya+7 = group g).
        const int gt = rslot(ya);
        const float4 ct0 = *(const float4*)&ring[gt][rr][16 + (jj << 3)];
        const float4 ct1 = *(const float4*)&ring[gt][rr][20 + (jj << 3)];

        // (3) Horizontal 31-tap: 10 aligned b128 LDS reads + register slide.
        {
            const float* vrow = &vbuf[rr * PHYSW];
            float w[40];
            #pragma unroll
            for (int k = 0; k < 10; ++k) {
                const float4 q = *(const float4*)&vrow[phys((jj << 3) + (k << 2))];
                w[4 * k + 0] = q.x; w[4 * k + 1] = q.y;
                w[4 * k + 2] = q.z; w[4 * k + 3] = q.w;
            }

            const float tc[8] = {ct0.x, ct0.y, ct0.z, ct0.w, ct1.x, ct1.y, ct1.z, ct1.w};
            const float oc[8] = {co0.x, co0.y, co0.z, co0.w, co1.x, co1.y, co1.z, co1.w};

            float s0 = 0.0f, s1 = 0.0f, s2 = 0.0f, s3 = 0.0f;
            #pragma unroll
            for (int c = 0; c < 28; c += 4) {
                s0 += w[c]; s1 += w[c + 1]; s2 += w[c + 2]; s3 += w[c + 3];
            }
            float s = (s0 + s1) + (s2 + s3) + w[28] + w[29] + w[30];
            #pragma unroll
            for (int m = 0; m < 8; ++m) {
                if (m > 0) s += w[30 + m] - w[m - 1];
                const float avg = s * INV_KK;
                const float wt  = 1.0f + 5.0f * fabsf(avg - tc[m]);
                const float sg  = 1.0f / (1.0f + __expf(-oc[m]));
                acc_i += sg * tc[m] * wt;
                acc_m += (tc[m] + sg) * wt;
            }
        }

        // (4) Land the staged rows in the ring (compiler inserts the per-wave
        //     vmcnt waits here — loads are ~1.5K cycles old by now).
        if (more) {
            const int gs = rslot(ya + 24);
            #pragma unroll
            for (int r = 0; r < 8; ++r) {
                ring[gs][r][t] = stA[r];
                if (st2) ring[gs][r][t + 256] = stB[r];
            }
            co0 = no0; co1 = no1;
        }
        __syncthreads();
    }

    // ---- block reduction ----
    #pragma unroll
    for (int off = 32; off > 0; off >>= 1) {
        acc_i += __shfl_down(acc_i, off);
        acc_m += __shfl_down(acc_m, off);
    }
    const int lane = t & 63;
    const int wv   = t >> 6;
    if (lane == 0) { red[wv * 2] = acc_i; red[wv * 2 + 1] = acc_m; }
    __syncthreads();
    if (t == 0) {
        atomicAdd(&acc[2 * b],     red[0] + red[2] + red[4] + red[6]);
        atomicAdd(&acc[2 * b + 1], red[1] + red[3] + red[5] + red[7]);
    }
}

__global__ void dice_final(const float* __restrict__ acc, float* __restrict__ out)
{
    const int t = threadIdx.x;
    float l = 0.0f;
    if (t < Bn) {
        const float I = acc[2 * t];
        const float M = acc[2 * t + 1];
        l = 1.0f - (2.0f * I + 0.001f) / (M + 0.001f);
    }
    #pragma unroll
    for (int off = 32; off > 0; off >>= 1) l += __shfl_down(l, off);
    if (t == 0) out[0] = l * (1.0f / 32.0f);
}

extern "C" void kernel_launch(void* const* d_in, const int* in_sizes, int n_in,
                              void* d_out, int out_size, void* d_ws, size_t ws_size,
                              hipStream_t stream)
{
    const float* logits = (const float*)d_in[0];   // "output" in reference
    const float* target = (const float*)d_in[1];
    float* acc = (float*)d_ws;                     // 64 floats: (I_b, M_b) per batch

    hipMemsetAsync(d_ws, 0, 64 * sizeof(float), stream);
    dice_main<<<dim3(Bn * 16), dim3(256), 0, stream>>>(logits, target, acc);
    dice_final<<<dim3(1), dim3(64), 0, stream>>>(acc, (float*)d_out);
}